// Round 6
// baseline (564.872 us; speedup 1.0000x reference)
//
#include <hip/hip_runtime.h>

#define Bn 64
#define Nn 1024
#define Cc 128

typedef _Float16 h8 __attribute__((ext_vector_type(8)));
typedef float f4v __attribute__((ext_vector_type(4)));
typedef unsigned long long u64;

// ---------------- featurize: x0 = nf @ W_in (fp16 grouped layout), ai/aj + exp tables ----------------
// grouped layout per batch: element (n,c) at ((n>>3)*128 + c)*8 + (n&7)
__global__ __launch_bounds__(256) void k_feat(
    const float* __restrict__ nf, const float* __restrict__ Win,
    const float* __restrict__ asrc, const float* __restrict__ adst,
    _Float16* __restrict__ X0, float* __restrict__ ai, float* __restrict__ aj,
    float* __restrict__ E, float* __restrict__ G, float* __restrict__ F, float* __restrict__ H) {
  int g = blockIdx.x; int b = g >> 7; int n0 = (g & 127) << 3;
  int t = threadIdx.x; int c = t >> 1; int h = t & 1;
  float w0 = Win[c], w1 = Win[Cc + c], w2 = Win[2 * Cc + c];
  float as_ = asrc[c], ad = adst[c];
  float ps[4], pd[4];
  _Float16 hv[4];
  #pragma unroll
  for (int r = 0; r < 4; r++) {
    int n = n0 + (h << 2) + r;
    const float* p = nf + ((size_t)(b << 10) + n) * 3;
    float x = p[0] * w0 + p[1] * w1 + p[2] * w2;
    hv[r] = (_Float16)x; ps[r] = x * as_; pd[r] = x * ad;
  }
  *(uint2*)(X0 + ((size_t)b << 17) + ((size_t)(g & 127) << 10) + (c << 3) + (h << 2)) = *(uint2*)hv;
  #pragma unroll
  for (int off = 32; off > 1; off >>= 1) {
    #pragma unroll
    for (int r = 0; r < 4; r++) { ps[r] += __shfl_down(ps[r], off, 64); pd[r] += __shfl_down(pd[r], off, 64); }
  }
  __shared__ float red[4][2][4][2];
  int lane = t & 63, wv = t >> 6;
  if (lane < 2) {
    #pragma unroll
    for (int r = 0; r < 4; r++) { red[wv][lane][r][0] = ps[r]; red[wv][lane][r][1] = pd[r]; }
  }
  __syncthreads();
  if (t < 8) {
    int hh = t >> 2, r = t & 3;
    float sa = 0.f, sd = 0.f;
    #pragma unroll
    for (int w = 0; w < 4; w++) { sa += red[w][hh][r][0]; sd += red[w][hh][r][1]; }
    int gi = (b << 10) + n0 + t;
    ai[gi] = sa; aj[gi] = sd;
    E[gi] = __expf(sa); G[gi] = __expf(0.2f * sa);
    F[gi] = __expf(sd); H[gi] = __expf(0.2f * sd);
  }
}

// ---------------- layer-2 scores from fp16 grouped x1 ----------------
__global__ __launch_bounds__(256) void k_scores2(
    const _Float16* __restrict__ X1,
    const float* __restrict__ asrc, const float* __restrict__ adst,
    float* __restrict__ ai, float* __restrict__ aj,
    float* __restrict__ E, float* __restrict__ G, float* __restrict__ F, float* __restrict__ H) {
  int g = blockIdx.x; int b = g >> 7; int n0 = (g & 127) << 3;
  int t = threadIdx.x; int c = t >> 1; int h = t & 1;
  float as_ = asrc[c], ad = adst[c];
  uint2 raw = *(const uint2*)(X1 + ((size_t)b << 17) + ((size_t)(g & 127) << 10) + (c << 3) + (h << 2));
  const _Float16* hp = (const _Float16*)&raw;
  float ps[4], pd[4];
  #pragma unroll
  for (int r = 0; r < 4; r++) { float x = (float)hp[r]; ps[r] = x * as_; pd[r] = x * ad; }
  #pragma unroll
  for (int off = 32; off > 1; off >>= 1) {
    #pragma unroll
    for (int r = 0; r < 4; r++) { ps[r] += __shfl_down(ps[r], off, 64); pd[r] += __shfl_down(pd[r], off, 64); }
  }
  __shared__ float red[4][2][4][2];
  int lane = t & 63, wv = t >> 6;
  if (lane < 2) {
    #pragma unroll
    for (int r = 0; r < 4; r++) { red[wv][lane][r][0] = ps[r]; red[wv][lane][r][1] = pd[r]; }
  }
  __syncthreads();
  if (t < 8) {
    int hh = t >> 2, r = t & 3;
    float sa = 0.f, sd = 0.f;
    #pragma unroll
    for (int w = 0; w < 4; w++) { sa += red[w][hh][r][0]; sd += red[w][hh][r][1]; }
    int gi = (b << 10) + n0 + t;
    ai[gi] = sa; aj[gi] = sd;
    E[gi] = __expf(sa); G[gi] = __expf(0.2f * sa);
    F[gi] = __expf(sd); H[gi] = __expf(0.2f * sd);
  }
}

// ------- barrier-free MFMA aggregation -------
// out[i,c] = relu( (1/den_i) * sum_j alpha_ij * x[j,c] ),  den_i = sum_j alpha_ij
// block: 64 i x 128 c, 4 waves; wave tile 16i x 128c (wave owns its rows).
// B-fragments loaded DIRECTLY from global (grouped layout == fragment layout);
// A-fragments cooked directly into registers. No K-loop barriers or LDS writes.
template <int LAYER>
__global__ __launch_bounds__(256, 3) void k_agg(
    const _Float16* __restrict__ X, const int* __restrict__ adj,
    const float* __restrict__ ai, const float* __restrict__ E, const float* __restrict__ G,
    const float* __restrict__ aj, const float* __restrict__ F, const float* __restrict__ H,
    u64* __restrict__ pm, _Float16* __restrict__ Y, float* __restrict__ xmp) {
  __shared__ __align__(16) char smem[24064];
  float* s_aj = (float*)smem;                            // 4 KB
  float* s_F  = (float*)(smem + 4096);                   // 4 KB
  float* s_H  = (float*)(smem + 8192);                   // 4 KB
  unsigned char* s_pm = (unsigned char*)(smem + 12288);  // 64 x 152 B
  float* s_col = (float*)(smem + 22016);                 // 4 x 128 floats (L2 epilogue)

  const int b = blockIdx.y, i0 = blockIdx.x << 6;
  const int tid = threadIdx.x;
  const int lane = tid & 63, w = tid >> 6;
  const int m = lane & 15, quad = lane >> 4;
  const int gbase = b << 10;

  // stage col-side arrays (aj, F, H) for all 1024 j
  ((float4*)s_aj)[tid] = ((const float4*)(aj + gbase))[tid];
  ((float4*)s_F)[tid]  = ((const float4*)(F + gbase))[tid];
  ((float4*)s_H)[tid]  = ((const float4*)(H + gbase))[tid];

  if (LAYER == 1) {
    // fused adjacency read + bit-pack; lane L packs j=16L..16L+15 of row r in-register,
    // stores direct to final LDS slot and to global pm (ushort view). No LDS read-back.
    ushort* pmu = (ushort*)pm;
    #pragma unroll 2
    for (int pass = 0; pass < 16; ++pass) {
      int r = (w << 4) + pass;
      const uint4* arow = (const uint4*)(adj + ((size_t)(gbase + i0 + r) << 10));
      uint4 v0 = arow[(lane << 2) | 0], v1 = arow[(lane << 2) | 1];
      uint4 v2 = arow[(lane << 2) | 2], v3 = arow[(lane << 2) | 3];
      unsigned int bits =
          (v0.x) | (v0.y << 1) | (v0.z << 2) | (v0.w << 3) |
          (v1.x << 4) | (v1.y << 5) | (v1.z << 6) | (v1.w << 7) |
          (v2.x << 8) | (v2.y << 9) | (v2.z << 10) | (v2.w << 11) |
          (v3.x << 12) | (v3.y << 13) | (v3.z << 14) | (v3.w << 15);
      *(ushort*)(s_pm + r * 152 + (lane << 1)) = (ushort)bits;
      pmu[((size_t)(gbase + i0 + r) << 6) + lane] = (ushort)bits;
    }
  } else {
    const u64* pmg = pm + (((size_t)(gbase + i0)) << 4);
    #pragma unroll
    for (int k = tid; k < 1024; k += 256) {
      int r = k >> 4, wd = k & 15;
      *(u64*)(s_pm + r * 152 + (wd << 3)) = pmg[k];
    }
  }

  // A-gen row constants: lane owns row_rel = w*16 + m (4 quads duplicate the row)
  const int irow = (w << 4) + m;
  const int gi = gbase + i0 + irow;
  const float ai_i = ai[gi];
  const float Ed = E[gi], Gd = G[gi];   // raw; den folded into epilogue
  float dsum = 0.f;

  f4v acc[8];
  #pragma unroll
  for (int ct = 0; ct < 8; ct++) { f4v z = {0.f, 0.f, 0.f, 0.f}; acc[ct] = z; }

  const h8* xb = (const h8*)(X + ((size_t)b << 17));
  const int prow = irow * 152;
  __syncthreads();  // prologue staging visible (only barrier before epilogue)

  for (int kt = 0; kt < 32; ++kt) {
    // B fragments straight from global (L2-resident; layout == fragment layout)
    const h8* bsrc = xb + (kt << 9) + (quad << 7) + m;
    h8 bf0 = bsrc[0],  bf1 = bsrc[16], bf2 = bsrc[32],  bf3 = bsrc[48];
    h8 bf4 = bsrc[64], bf5 = bsrc[80], bf6 = bsrc[96],  bf7 = bsrc[112];
    // A fragment in-register: alpha(row=irow, j = kt*32 + quad*8 + jj)
    const int j0 = (kt << 5) + (quad << 3);
    float aw[8], fw[8], hw[8];
    *(float4*)&aw[0] = *(const float4*)&s_aj[j0]; *(float4*)&aw[4] = *(const float4*)&s_aj[j0 + 4];
    *(float4*)&fw[0] = *(const float4*)&s_F[j0];  *(float4*)&fw[4] = *(const float4*)&s_F[j0 + 4];
    *(float4*)&hw[0] = *(const float4*)&s_H[j0];  *(float4*)&hw[4] = *(const float4*)&s_H[j0 + 4];
    unsigned int mb = s_pm[prow + (kt << 2) + quad];
    h8 af;
    #pragma unroll
    for (int jj = 0; jj < 8; jj++) {
      float e = ai_i + aw[jj];
      bool pos = e > 0.f;
      float wi_ = pos ? Ed : Gd;
      float wj_ = pos ? fw[jj] : hw[jj];
      float val = ((mb >> jj) & 1u) ? wi_ * wj_ : 0.f;
      dsum += val;
      af[jj] = (_Float16)val;
    }
    acc[0] = __builtin_amdgcn_mfma_f32_16x16x32_f16(af, bf0, acc[0], 0, 0, 0);
    acc[1] = __builtin_amdgcn_mfma_f32_16x16x32_f16(af, bf1, acc[1], 0, 0, 0);
    acc[2] = __builtin_amdgcn_mfma_f32_16x16x32_f16(af, bf2, acc[2], 0, 0, 0);
    acc[3] = __builtin_amdgcn_mfma_f32_16x16x32_f16(af, bf3, acc[3], 0, 0, 0);
    acc[4] = __builtin_amdgcn_mfma_f32_16x16x32_f16(af, bf4, acc[4], 0, 0, 0);
    acc[5] = __builtin_amdgcn_mfma_f32_16x16x32_f16(af, bf5, acc[5], 0, 0, 0);
    acc[6] = __builtin_amdgcn_mfma_f32_16x16x32_f16(af, bf6, acc[6], 0, 0, 0);
    acc[7] = __builtin_amdgcn_mfma_f32_16x16x32_f16(af, bf7, acc[7], 0, 0, 0);
  }

  // per-row denominator: sum lane partials over the 4 quads (same m = same row)
  dsum += __shfl_xor(dsum, 16, 64);
  dsum += __shfl_xor(dsum, 32, 64);
  // C/D rows for this lane are quad*4+r -> fetch those rows' dens (held at lanes m'=quad*4+r)
  float rd[4];
  #pragma unroll
  for (int r = 0; r < 4; r++) rd[r] = 1.0f / __shfl(dsum, (quad << 2) + r, 64);

  if (LAYER == 1) {
    // direct grouped-layout store: n = i0 + w*16 + quad*4 + r, c = ct*16 + m
    const int g8 = ((i0 + (w << 4)) >> 3) + (quad >> 1);
    _Float16* yb = Y + ((size_t)b << 17) + (size_t)g8 * 1024 + ((quad & 1) << 2);
    #pragma unroll
    for (int ct = 0; ct < 8; ct++) {
      int c = (ct << 4) + m;
      _Float16 hv[4];
      #pragma unroll
      for (int r = 0; r < 4; r++) hv[r] = (_Float16)fmaxf(acc[ct][r] * rd[r], 0.f);
      *(uint2*)(yb + c * 8) = *(uint2*)hv;
    }
  } else {
    // node-mean partials: per-lane col sums over its 4 rows, quad-reduce -> 16 rows/wave,
    // one LDS pass to combine the 4 waves.
    #pragma unroll
    for (int ct = 0; ct < 8; ct++) {
      float cs = (fmaxf(acc[ct][0] * rd[0], 0.f) + fmaxf(acc[ct][1] * rd[1], 0.f))
               + (fmaxf(acc[ct][2] * rd[2], 0.f) + fmaxf(acc[ct][3] * rd[3], 0.f));
      cs += __shfl_xor(cs, 16, 64);
      cs += __shfl_xor(cs, 32, 64);
      if (quad == 0) s_col[(w << 7) + (ct << 4) + m] = cs;
    }
    __syncthreads();
    if (tid < 128) {
      float s = s_col[tid] + s_col[128 + tid] + s_col[256 + tid] + s_col[384 + tid];
      xmp[(((b << 4) + blockIdx.x) << 7) + tid] = s;
    }
  }
}

// ---------------- fused MLP head (sums the 16 mean-partials) ----------------
__global__ __launch_bounds__(256) void k_head(
    const float* __restrict__ xmp, const float* __restrict__ W1, const float* __restrict__ b1,
    const float* __restrict__ W2, const float* __restrict__ b2,
    const float* __restrict__ Wpi, const float* __restrict__ bpi,
    const float* __restrict__ Wv, const float* __restrict__ bv,
    float* __restrict__ out) {
  int b = blockIdx.x, t = threadIdx.x;
  __shared__ float xs[128], h1[256], h2[128], red[4];
  if (t < 128) {
    const float* p = xmp + ((size_t)b << 11);
    float s = 0.f;
    #pragma unroll
    for (int xb = 0; xb < 16; xb++) s += p[(xb << 7) + t];
    xs[t] = s * (1.f / 1024.f);
  }
  __syncthreads();
  float s = 0.f;
  #pragma unroll 8
  for (int k = 0; k < 128; k++) s += xs[k] * W1[k * 256 + t];
  h1[t] = fmaxf(s + b1[t], 0.f);
  __syncthreads();
  if (t < 128) {
    float s2 = 0.f;
    #pragma unroll 8
    for (int k = 0; k < 256; k++) s2 += h1[k] * W2[k * 128 + t];
    h2[t] = fmaxf(s2 + b2[t], 0.f);
  }
  __syncthreads();
  float lg[4];
  #pragma unroll
  for (int q = 0; q < 4; q++) {
    int o = t + (q << 8);
    float s3 = 0.f;
    #pragma unroll 8
    for (int k = 0; k < 128; k++) s3 += h2[k] * Wpi[k * 1024 + o];
    lg[q] = s3 + bpi[o];
  }
  float mx = fmaxf(fmaxf(lg[0], lg[1]), fmaxf(lg[2], lg[3]));
  #pragma unroll
  for (int off = 32; off > 0; off >>= 1) mx = fmaxf(mx, __shfl_down(mx, off, 64));
  if ((t & 63) == 0) red[t >> 6] = mx;
  __syncthreads();
  mx = fmaxf(fmaxf(red[0], red[1]), fmaxf(red[2], red[3]));
  __syncthreads();
  float ex[4]; float sum = 0.f;
  #pragma unroll
  for (int q = 0; q < 4; q++) { ex[q] = __expf(lg[q] - mx); sum += ex[q]; }
  #pragma unroll
  for (int off = 32; off > 0; off >>= 1) sum += __shfl_down(sum, off, 64);
  if ((t & 63) == 0) red[t >> 6] = sum;
  __syncthreads();
  sum = red[0] + red[1] + red[2] + red[3];
  float rs = 1.0f / sum;
  #pragma unroll
  for (int q = 0; q < 4; q++) out[((size_t)b << 10) + t + (q << 8)] = ex[q] * rs;
  __syncthreads();
  float vp = (t < 128) ? h2[t] * Wv[t] : 0.f;
  #pragma unroll
  for (int off = 32; off > 0; off >>= 1) vp += __shfl_down(vp, off, 64);
  if ((t & 63) == 0) red[t >> 6] = vp;
  __syncthreads();
  if (t == 0) out[65536 + b] = red[0] + red[1] + red[2] + red[3] + bv[0];
}

extern "C" void kernel_launch(void* const* d_in, const int* in_sizes, int n_in,
                              void* d_out, int out_size, void* d_ws, size_t ws_size,
                              hipStream_t stream) {
  const float* nf    = (const float*)d_in[0];
  const int*   adj   = (const int*)  d_in[1];
  const float* Win   = (const float*)d_in[2];
  const float* asrc  = (const float*)d_in[3];
  const float* adst  = (const float*)d_in[4];
  const float* asrc2 = (const float*)d_in[5];
  const float* adst2 = (const float*)d_in[6];
  const float* W1    = (const float*)d_in[7];
  const float* b1    = (const float*)d_in[8];
  const float* W2    = (const float*)d_in[9];
  const float* b2    = (const float*)d_in[10];
  const float* Wpi   = (const float*)d_in[11];
  const float* bpi   = (const float*)d_in[12];
  const float* Wv    = (const float*)d_in[13];
  const float* bv    = (const float*)d_in[14];
  float* out = (float*)d_out;

  char* ws = (char*)d_ws;
  _Float16* x0 = (_Float16*)(ws);                                // 16.78 MB
  _Float16* x1 = (_Float16*)(ws + 16777216);                     // 16.78 MB
  u64* pm = (u64*)(ws + 33554432);                               // 8.39 MB
  char* S = ws + 41943040;
  float* ai1 = (float*)(S + 0 * 262144);
  float* aj1 = (float*)(S + 1 * 262144);
  float* E1  = (float*)(S + 2 * 262144);
  float* G1  = (float*)(S + 3 * 262144);
  float* F1  = (float*)(S + 4 * 262144);
  float* H1  = (float*)(S + 5 * 262144);
  float* ai2 = (float*)(S + 6 * 262144);
  float* aj2 = (float*)(S + 7 * 262144);
  float* E2  = (float*)(S + 8 * 262144);
  float* G2  = (float*)(S + 9 * 262144);
  float* F2  = (float*)(S + 10 * 262144);
  float* H2  = (float*)(S + 11 * 262144);
  float* xmp = (float*)(S + 12 * 262144);                        // 512 KB partials

  k_feat<<<8192, 256, 0, stream>>>(nf, Win, asrc, adst, x0, ai1, aj1, E1, G1, F1, H1);
  dim3 ag(16, Bn);
  k_agg<1><<<ag, 256, 0, stream>>>(x0, adj, ai1, E1, G1, aj1, F1, H1, pm, x1, nullptr);
  k_scores2<<<8192, 256, 0, stream>>>(x1, asrc2, adst2, ai2, aj2, E2, G2, F2, H2);
  k_agg<2><<<ag, 256, 0, stream>>>(x1, nullptr, ai2, E2, G2, aj2, F2, H2, pm, nullptr, xmp);
  k_head<<<Bn, 256, 0, stream>>>(xmp, W1, b1, W2, b2, Wpi, bpi, Wv, bv, out);
}